// Round 5
// baseline (411.022 us; speedup 1.0000x reference)
//
#include <hip/hip_runtime.h>
#include <hip/hip_fp16.h>
#include <stdint.h>

#define GAS __attribute__((address_space(1)))
#define LAS __attribute__((address_space(3)))

static constexpr int K_TOT = 4096;
static constexpr int N_TOT = 4096;
static constexpr int NO_CAP = 64;   // max tracked outlier columns (actual data: 8)
static constexpr float SIGMA = 20.0f;

typedef int v4i __attribute__((ext_vector_type(4)));

// ---------------- init: zero outlier mask ----------------
__global__ __launch_bounds__(256) void k_init(int* __restrict__ mask) {
  mask[blockIdx.x * 256 + threadIdx.x] = 0;
}

// ---------------- activation: row absmax -> scale_row, int8 quant, outlier mask ----
__global__ __launch_bounds__(256) void k_quant_x(const float* __restrict__ x,
                                                 int8_t* __restrict__ qx,
                                                 float* __restrict__ scale_row,
                                                 int* __restrict__ mask) {
  const int lane = threadIdx.x & 63;
  const int wid  = threadIdx.x >> 6;
  const int m = blockIdx.x * 4 + wid;
  const float* xr = x + (size_t)m * K_TOT;

  float4 v[16];
  float amax = 0.0f;
#pragma unroll
  for (int it = 0; it < 16; ++it) {
    const int k0 = it * 256 + lane * 4;
    v[it] = *(const float4*)(xr + k0);
    const float a0 = fabsf(v[it].x), a1 = fabsf(v[it].y);
    const float a2 = fabsf(v[it].z), a3 = fabsf(v[it].w);
    amax = fmaxf(amax, fmaxf(fmaxf(a0, a1), fmaxf(a2, a3)));
    if (a0 > SIGMA) mask[k0 + 0] = 1;
    if (a1 > SIGMA) mask[k0 + 1] = 1;
    if (a2 > SIGMA) mask[k0 + 2] = 1;
    if (a3 > SIGMA) mask[k0 + 3] = 1;
  }
#pragma unroll
  for (int off = 32; off > 0; off >>= 1)
    amax = fmaxf(amax, __shfl_xor(amax, off));

  const float s = fmaxf(amax / 127.0f, 1e-8f);
  if (lane == 0) scale_row[m] = s;

  int8_t* qr = qx + (size_t)m * K_TOT;
#pragma unroll
  for (int it = 0; it < 16; ++it) {
    const int k0 = it * 256 + lane * 4;
    const int q0 = (int)rintf(fminf(fmaxf(v[it].x / s, -128.0f), 127.0f));
    const int q1 = (int)rintf(fminf(fmaxf(v[it].y / s, -128.0f), 127.0f));
    const int q2 = (int)rintf(fminf(fmaxf(v[it].z / s, -128.0f), 127.0f));
    const int q3 = (int)rintf(fminf(fmaxf(v[it].w / s, -128.0f), 127.0f));
    const uint32_t p = (uint32_t)(q0 & 0xFF) | ((uint32_t)(q1 & 0xFF) << 8) |
                       ((uint32_t)(q2 & 0xFF) << 16) | ((uint32_t)(q3 & 0xFF) << 24);
    *(uint32_t*)(qr + k0) = p;
  }
}

// ---------------- compact outlier indices (ordered, single block) ----------------
__global__ __launch_bounds__(256) void k_compact(const int* __restrict__ mask,
                                                 uint8_t* __restrict__ bitbytes,
                                                 int* __restrict__ ind,
                                                 int* __restrict__ count) {
  const int t = threadIdx.x;
  int local[16];
  int cnt = 0;
  uint32_t bits = 0;
#pragma unroll
  for (int j = 0; j < 16; ++j) {
    const int k = t * 16 + j;
    if (mask[k]) { bits |= (1u << j); local[cnt++] = k; }
  }
  bitbytes[2 * t]     = (uint8_t)(bits & 0xFF);
  bitbytes[2 * t + 1] = (uint8_t)((bits >> 8) & 0xFF);

  const int lane = t & 63, wid = t >> 6;
  int incl = cnt;
  for (int off = 1; off < 64; off <<= 1) {
    int o = __shfl_up(incl, off);
    if (lane >= off) incl += o;
  }
  __shared__ int wsum[4];
  if (lane == 63) wsum[wid] = incl;
  __syncthreads();
  int base = 0;
  for (int i = 0; i < wid; ++i) base += wsum[i];
  const int excl = base + incl - cnt;
  for (int j = 0; j < cnt; ++j) {
    const int pos = excl + j;
    if (pos < NO_CAP) ind[pos] = local[j];
  }
  if (t == 255) {
    const int tot = excl + cnt;
    *count = tot > NO_CAP ? NO_CAP : tot;
  }
}

// ---------------- weight: zero outlier cols, row absmax -> scale_col, int8 quant, wo gather
__global__ __launch_bounds__(256) void k_quant_w(const float* __restrict__ w,
                                                 const uint8_t* __restrict__ bitbytes,
                                                 const int* __restrict__ ind,
                                                 const int* __restrict__ count,
                                                 int8_t* __restrict__ qw,
                                                 float* __restrict__ scale_col,
                                                 float* __restrict__ wo) {
  const int lane = threadIdx.x & 63;
  const int wid  = threadIdx.x >> 6;
  const int n = blockIdx.x * 4 + wid;
  const float* wr_ = w + (size_t)n * K_TOT;

  float4 v[16];
  float amax = 0.0f;
#pragma unroll
  for (int it = 0; it < 16; ++it) {
    const int k0 = it * 256 + lane * 4;
    v[it] = *(const float4*)(wr_ + k0);
    const uint32_t b = (uint32_t)(bitbytes[k0 >> 3] >> (k0 & 7));
    if (b & 1u) v[it].x = 0.0f;
    if (b & 2u) v[it].y = 0.0f;
    if (b & 4u) v[it].z = 0.0f;
    if (b & 8u) v[it].w = 0.0f;
    amax = fmaxf(amax, fmaxf(fmaxf(fabsf(v[it].x), fabsf(v[it].y)),
                             fmaxf(fabsf(v[it].z), fabsf(v[it].w))));
  }
#pragma unroll
  for (int off = 32; off > 0; off >>= 1)
    amax = fmaxf(amax, __shfl_xor(amax, off));

  float s = amax / 127.0f;
  s = __half2float(__float2half_rn(s));
  s = fmaxf(s, 1e-8f);
  if (lane == 0) scale_col[n] = s;

  int8_t* qr = qw + (size_t)n * K_TOT;
#pragma unroll
  for (int it = 0; it < 16; ++it) {
    const int k0 = it * 256 + lane * 4;
    const int q0 = (int)rintf(fminf(fmaxf(v[it].x / s, -128.0f), 127.0f));
    const int q1 = (int)rintf(fminf(fmaxf(v[it].y / s, -128.0f), 127.0f));
    const int q2 = (int)rintf(fminf(fmaxf(v[it].z / s, -128.0f), 127.0f));
    const int q3 = (int)rintf(fminf(fmaxf(v[it].w / s, -128.0f), 127.0f));
    const uint32_t p = (uint32_t)(q0 & 0xFF) | ((uint32_t)(q1 & 0xFF) << 8) |
                       ((uint32_t)(q2 & 0xFF) << 16) | ((uint32_t)(q3 & 0xFF) << 24);
    *(uint32_t*)(qr + k0) = p;
  }

  const int cnt = *count;
  if (lane < NO_CAP) {
    float val = 0.0f;
    if (lane < cnt) val = wr_[ind[lane]];
    wo[(size_t)n * NO_CAP + lane] = val;
  }
}

// ---------------- gather compact outlier activations (fp32), zero-pad to >=8 ----
__global__ __launch_bounds__(256) void k_gather_xo(const float* __restrict__ x,
                                                   const int* __restrict__ ind,
                                                   const int* __restrict__ count,
                                                   float* __restrict__ xo) {
  const int m = blockIdx.x * 256 + threadIdx.x;
  const int cnt = *count;
  const int fill = cnt < 8 ? 8 : cnt;
  for (int j = 0; j < fill; ++j) {
    float val = 0.0f;
    if (j < cnt) val = x[(size_t)m * K_TOT + ind[j]];
    xo[(size_t)m * NO_CAP + j] = val;
  }
}

// =====================================================================
// int8 GEMM: 256x256 tile, BK=128B, 4-phase/K-tile with READ-AHEAD.
// LDS 160 KB: A triple-buffered (3 x 32KB at 0/32768/65536),
//             B double-buffered (2 x 32KB at 98304/131072).
// Reads/phase {8,0,8,8} ds_read_b128, all >=1 phase ahead of their MFMA:
//   p0(t): LDA47(t)        -> used p2,p3(t)
//   p2(t): LDA03(t+1)      -> used p0,p1(t+1)
//   p3(t): LDB0,LDB1(t+1)  -> used p0..p3(t+1)   (b0 register ping-pong)
// Stages: B(t+2)@p2(t), A(t+3)@p3(t). Counted vmcnt(8) at p1,p2 only
// (retires A(t+1) / B(t+1)); never 0 until the 2-tile tail.
// No manual lgkmcnt: compiler emits minimal counted waits for its loads.
// =====================================================================
#define STAGE_A2(kt, AB) do { \
  __builtin_amdgcn_global_load_lds((const GAS void*)(qx + gA0 + (size_t)(kt)*128), \
      (LAS void*)(smem + (AB) + ldsOff0), 16, 0, 0); \
  __builtin_amdgcn_global_load_lds((const GAS void*)(qx + gA1 + (size_t)(kt)*128), \
      (LAS void*)(smem + (AB) + ldsOff1), 16, 0, 0); \
  __builtin_amdgcn_global_load_lds((const GAS void*)(qx + gA0 + 128*(size_t)K_TOT + (size_t)(kt)*128), \
      (LAS void*)(smem + (AB) + 16384 + ldsOff0), 16, 0, 0); \
  __builtin_amdgcn_global_load_lds((const GAS void*)(qx + gA1 + 128*(size_t)K_TOT + (size_t)(kt)*128), \
      (LAS void*)(smem + (AB) + 16384 + ldsOff1), 16, 0, 0); \
} while (0)

#define STAGE_B2(kt, BPAR) do { \
  __builtin_amdgcn_global_load_lds((const GAS void*)(qw + gB0 + (size_t)(kt)*128), \
      (LAS void*)(smem + 98304 + (BPAR)*32768 + ldsOff0), 16, 0, 0); \
  __builtin_amdgcn_global_load_lds((const GAS void*)(qw + gB1 + (size_t)(kt)*128), \
      (LAS void*)(smem + 98304 + (BPAR)*32768 + ldsOff1), 16, 0, 0); \
  __builtin_amdgcn_global_load_lds((const GAS void*)(qw + gB0 + 128*(size_t)K_TOT + (size_t)(kt)*128), \
      (LAS void*)(smem + 98304 + (BPAR)*32768 + 16384 + ldsOff0), 16, 0, 0); \
  __builtin_amdgcn_global_load_lds((const GAS void*)(qw + gB1 + 128*(size_t)K_TOT + (size_t)(kt)*128), \
      (LAS void*)(smem + 98304 + (BPAR)*32768 + 16384 + ldsOff1), 16, 0, 0); \
} while (0)

#define LDA_(dst, mq, ABOFF) do { \
  _Pragma("unroll") for (int i_ = 0; i_ < 4; ++i_) \
  _Pragma("unroll") for (int ks_ = 0; ks_ < 2; ++ks_) \
    dst[i_][ks_] = *(const v4i*)(smem + (ABOFF) + aWave + ((mq)*4 + i_)*2048 + ks_*1024 + rcSwz); \
} while (0)

#define LDB_(dst, nq, BPAR) do { \
  _Pragma("unroll") for (int i_ = 0; i_ < 2; ++i_) \
  _Pragma("unroll") for (int ks_ = 0; ks_ < 2; ++ks_) \
    dst[i_][ks_] = *(const v4i*)(smem + 98304 + (BPAR)*32768 + bWave + (bColBlk + (nq)*2 + i_)*2048 + ks_*1024 + rcSwz); \
} while (0)

#define MM_(asrc, bsrc, MQ, NQ) do { \
  _Pragma("unroll") for (int i_ = 0; i_ < 4; ++i_) \
  _Pragma("unroll") for (int j_ = 0; j_ < 2; ++j_) \
  _Pragma("unroll") for (int ks_ = 0; ks_ < 2; ++ks_) \
    acc[(MQ)*4 + i_][(NQ)*2 + j_] = __builtin_amdgcn_mfma_i32_16x16x64_i8( \
        asrc[i_][ks_], bsrc[j_][ks_], acc[(MQ)*4 + i_][(NQ)*2 + j_], 0, 0, 0); \
} while (0)

#define BAR()  __builtin_amdgcn_s_barrier()
#define PRIO1  __builtin_amdgcn_s_setprio(1)
#define PRIO0  __builtin_amdgcn_s_setprio(0)
#define VMC(n) asm volatile("s_waitcnt vmcnt(" #n ")" ::: "memory")

#define TILE(T0, AC, AN, BPAR, B0C, B0N) do {                                 \
  /* p0: Q(0,0)=a03*b0; read-ahead A47(t) */                                  \
  LDA_(a47, 1, AC);                                                           \
  BAR();                                                                      \
  PRIO1; MM_(a03, B0C, 0, 0); PRIO0;                                          \
  BAR();                                                                      \
  /* p1: Q(0,1)=a03*b1; retire A(t+1) */                                      \
  BAR();                                                                      \
  PRIO1; MM_(a03, b1, 0, 1); PRIO0;                                           \
  if ((T0) < NT - 2) { VMC(8); } else if ((T0) == NT - 2) { VMC(4); }         \
  BAR();                                                                      \
  /* p2: Q(1,1)=a47*b1; read-ahead A03(t+1); stage B(t+2); retire B(t+1) */   \
  LDA_(a03, 0, AN);                                                           \
  if ((T0) + 2 < NT) { STAGE_B2((T0) + 2, BPAR); }                            \
  BAR();                                                                      \
  PRIO1; MM_(a47, b1, 1, 1); PRIO0;                                           \
  if ((T0) < NT - 2) { VMC(8); } else if ((T0) == NT - 2) { VMC(0); }         \
  BAR();                                                                      \
  /* p3: Q(1,0)=a47*b0; read-ahead B0,B1(t+1); stage A(t+3) */                \
  LDB_(B0N, 0, (BPAR) ^ 1);                                                   \
  LDB_(b1, 1, (BPAR) ^ 1);                                                    \
  if ((T0) + 3 < NT) { STAGE_A2((T0) + 3, AC); }                              \
  BAR();                                                                      \
  PRIO1; MM_(a47, B0C, 1, 0); PRIO0;                                          \
  BAR();                                                                      \
} while (0)

__global__ __launch_bounds__(512, 2) void k_gemm8(const int8_t* __restrict__ qx,
                                                  const int8_t* __restrict__ qw,
                                                  const float* __restrict__ scale_row,
                                                  const float* __restrict__ scale_col,
                                                  const float* __restrict__ xo,
                                                  const float* __restrict__ wo,
                                                  const int* __restrict__ countp,
                                                  const float* __restrict__ bias,
                                                  float* __restrict__ out) {
  extern __shared__ int8_t smem[];
  constexpr int NT = K_TOT / 128;   // 32 K-tiles

  const int t = threadIdx.x;
  const int lane = t & 63;
  const int wid = t >> 6;
  const int wm = wid >> 2;          // 0..1
  const int wn = wid & 3;           // 0..3

  // T1: XCD-aware bijective block swizzle (nwg = 512, divisible by 8)
  const int nbx = gridDim.x;
  const int nwg = gridDim.x * gridDim.y;
  int lin = blockIdx.y * nbx + blockIdx.x;
  lin = (lin & 7) * (nwg >> 3) + (lin >> 3);
  const int bm0 = (lin % nbx) * 256;
  const int bn0 = (lin / nbx) * 256;

  // staging addresses (pre-swizzled source, rule #21): thread covers 16B chunk
  // f = l*512 + t of a 16KB half-tile
  uint32_t gA0, gA1, gB0, gB1;
  {
    const int f0 = t, f1 = 512 + t;
    const int rb0 = f0 >> 7, kb0 = (f0 >> 6) & 1, r0 = (f0 >> 2) & 15, c0 = f0 & 3;
    const int rb1 = f1 >> 7, kb1 = (f1 >> 6) & 1, r1 = (f1 >> 2) & 15, c1 = f1 & 3;
    const int c0s = c0 ^ ((r0 & 8) ? 2 : 0);
    const int c1s = c1 ^ ((r1 & 8) ? 2 : 0);
    gA0 = (uint32_t)((bm0 + rb0 * 16 + r0) * K_TOT + kb0 * 64 + c0s * 16);
    gA1 = (uint32_t)((bm0 + rb1 * 16 + r1) * K_TOT + kb1 * 64 + c1s * 16);
    gB0 = (uint32_t)((bn0 + rb0 * 16 + r0) * K_TOT + kb0 * 64 + c0s * 16);
    gB1 = (uint32_t)((bn0 + rb1 * 16 + r1) * K_TOT + kb1 * 64 + c1s * 16);
  }
  const int ldsOff0 = wid * 1024;          // wave-uniform; lane*16 added by HW
  const int ldsOff1 = 8192 + wid * 1024;

  // swizzled ds_read fragment addressing
  const int rr = lane & 15;
  const int rcSwz = rr * 64 + (((lane >> 4) * 16) ^ ((lane & 8) ? 32 : 0));
  const int aWave = wm * 16384;
  const int bWave = (wn >> 1) * 16384;
  const int bColBlk = (wn & 1) * 4;

  v4i acc[8][4];
#pragma unroll
  for (int i = 0; i < 8; ++i)
#pragma unroll
    for (int j = 0; j < 4; ++j) acc[i][j] = (v4i){0, 0, 0, 0};
  v4i a03[4][2], a47[4][2], b0a[2][2], b0b[2][2], b1[2][2];

  // A LDS buffer byte-offsets rotate cur->next->next2 each tile
  int ac = 0, an = 32768, aw = 65536;

  // ---- prologue: stage A(0),B(0),A(1); retire tile 0; pre-read a03(0),b0(0),b1(0);
  //      stage B(1),A(2)  -> in-flight {A(1),B(1),A(2)} = 12, steady-state invariant
  STAGE_A2(0, 0);
  STAGE_B2(0, 0);
  STAGE_A2(1, 32768);
  VMC(4);
  BAR();
  LDA_(a03, 0, 0);
  LDB_(b0a, 0, 0);
  LDB_(b1, 1, 0);
  STAGE_B2(1, 1);
  STAGE_A2(2, 65536);

  for (int t0 = 0; t0 < NT; t0 += 2) {
    TILE(t0, ac, an, 0, b0a, b0b);
    { int tmp = ac; ac = an; an = aw; aw = tmp; }
    TILE(t0 + 1, ac, an, 1, b0b, b0a);
    { int tmp = ac; ac = an; an = aw; aw = tmp; }
  }

  // ---- epilogue: y = acc*sr*sc + outlier_dot + bias, rounded to fp16 precision ----
  const int cnt = *countp;
  const int col = lane & 15;
  const int row4 = (lane >> 4) * 4;

  float scn[4], bzn[4];
  int nn[4];
#pragma unroll
  for (int ni = 0; ni < 4; ++ni) {
    const int n = bn0 + wn * 64 + ni * 16 + col;
    nn[ni] = n;
    scn[ni] = scale_col[n];
    bzn[ni] = bias[n];
  }

  if (cnt <= 8) {
    float wv[4][8];
#pragma unroll
    for (int ni = 0; ni < 4; ++ni)
#pragma unroll
      for (int j = 0; j < 8; ++j) wv[ni][j] = wo[(size_t)nn[ni] * NO_CAP + j];
#pragma unroll
    for (int mi = 0; mi < 8; ++mi) {
#pragma unroll
      for (int r = 0; r < 4; ++r) {
        const int m = bm0 + wm * 128 + mi * 16 + row4 + r;
        const float srm = scale_row[m];
        float xv[8];
#pragma unroll
        for (int j = 0; j < 8; ++j) xv[j] = xo[(size_t)m * NO_CAP + j];
#pragma unroll
        for (int ni = 0; ni < 4; ++ni) {
          float y = (float)acc[mi][ni][r] * srm * scn[ni];
#pragma unroll
          for (int j = 0; j < 8; ++j) y += xv[j] * wv[ni][j];
          y += bzn[ni];
          out[(size_t)m * N_TOT + nn[ni]] = __half2float(__float2half_rn(y));
        }
      }
    }
  } else {
#pragma unroll
    for (int mi = 0; mi < 8; ++mi) {
#pragma unroll
      for (int r = 0; r < 4; ++r) {
        const int m = bm0 + wm * 128 + mi * 16 + row4 + r;
        const float srm = scale_row[m];
#pragma unroll
        for (int ni = 0; ni < 4; ++ni) {
          float y = (float)acc[mi][ni][r] * srm * scn[ni];
          for (int j = 0; j < cnt; ++j)
            y += xo[(size_t)m * NO_CAP + j] * wo[(size_t)nn[ni] * NO_CAP + j];
          y += bzn[ni];
          out[(size_t)m * N_TOT + nn[ni]] = __half2float(__float2half_rn(y));
        }
      }
    }
  }
}

extern "C" void kernel_launch(void* const* d_in, const int* in_sizes, int n_in,
                              void* d_out, int out_size, void* d_ws, size_t ws_size,
                              hipStream_t stream) {
  const float* x    = (const float*)d_in[0];
  const float* w    = (const float*)d_in[1];
  const float* bias = (const float*)d_in[2];
  float* out        = (float*)d_out;

  const int M = in_sizes[0] / K_TOT;   // 8192 for B=4,S=2048

  char* ws = (char*)d_ws;
  const size_t OFF_SR   = 0;
  const size_t OFF_SC   = OFF_SR + sizeof(float) * (size_t)M;
  const size_t OFF_MASK = OFF_SC + sizeof(float) * (size_t)N_TOT;
  const size_t OFF_IND  = OFF_MASK + sizeof(int) * (size_t)K_TOT;
  const size_t OFF_CNT  = OFF_IND + sizeof(int) * (size_t)NO_CAP;
  const size_t OFF_BB   = OFF_CNT + 256;
  const size_t OFF_XO   = (OFF_BB + (size_t)(K_TOT / 8) + 255) & ~(size_t)255;
  const size_t OFF_WO   = OFF_XO + sizeof(float) * (size_t)M * NO_CAP;
  const size_t OFF_QX   = (OFF_WO + sizeof(float) * (size_t)N_TOT * NO_CAP + 255) & ~(size_t)255;
  const size_t OFF_QW   = OFF_QX + (size_t)M * K_TOT;

  float* scale_row  = (float*)(ws + OFF_SR);
  float* scale_col  = (float*)(ws + OFF_SC);
  int* mask         = (int*)(ws + OFF_MASK);
  int* ind          = (int*)(ws + OFF_IND);
  int* count        = (int*)(ws + OFF_CNT);
  uint8_t* bitbytes = (uint8_t*)(ws + OFF_BB);
  float* xo         = (float*)(ws + OFF_XO);
  float* wo         = (float*)(ws + OFF_WO);
  int8_t* qx        = (int8_t*)(ws + OFF_QX);
  int8_t* qw        = (int8_t*)(ws + OFF_QW);

  // allow 160 KiB dynamic LDS for the read-ahead GEMM (A triple + B double buffer)
  hipFuncSetAttribute((const void*)k_gemm8,
                      hipFuncAttributeMaxDynamicSharedMemorySize, 163840);

  hipLaunchKernelGGL(k_init, dim3(K_TOT / 256), dim3(256), 0, stream, mask);
  hipLaunchKernelGGL(k_quant_x, dim3(M / 4), dim3(256), 0, stream, x, qx, scale_row, mask);
  hipLaunchKernelGGL(k_compact, dim3(1), dim3(256), 0, stream, mask, bitbytes, ind, count);
  hipLaunchKernelGGL(k_quant_w, dim3(N_TOT / 4), dim3(256), 0, stream,
                     w, bitbytes, ind, count, qw, scale_col, wo);
  hipLaunchKernelGGL(k_gather_xo, dim3(M / 256), dim3(256), 0, stream, x, ind, count, xo);
  hipLaunchKernelGGL(k_gemm8, dim3(M / 256, N_TOT / 256), dim3(512), 163840, stream,
                     qx, qw, scale_row, scale_col, xo, wo, count, bias, out);
}

// Round 6
// 291.704 us; speedup vs baseline: 1.4090x; 1.4090x over previous
//
#include <hip/hip_runtime.h>
#include <hip/hip_fp16.h>
#include <stdint.h>

#define GAS __attribute__((address_space(1)))
#define LAS __attribute__((address_space(3)))

static constexpr int K_TOT = 4096;
static constexpr int N_TOT = 4096;
static constexpr int NO_CAP = 64;   // max tracked outlier columns (actual data: 8)
static constexpr float SIGMA = 20.0f;

typedef int v4i __attribute__((ext_vector_type(4)));
typedef int v16i __attribute__((ext_vector_type(16)));

// ---------------- init: zero outlier mask ----------------
__global__ __launch_bounds__(256) void k_init(int* __restrict__ mask) {
  mask[blockIdx.x * 256 + threadIdx.x] = 0;
}

// ---------------- activation: row absmax -> scale_row, int8 quant, outlier mask ----
__global__ __launch_bounds__(256) void k_quant_x(const float* __restrict__ x,
                                                 int8_t* __restrict__ qx,
                                                 float* __restrict__ scale_row,
                                                 int* __restrict__ mask) {
  const int lane = threadIdx.x & 63;
  const int wid  = threadIdx.x >> 6;
  const int m = blockIdx.x * 4 + wid;
  const float* xr = x + (size_t)m * K_TOT;

  float4 v[16];
  float amax = 0.0f;
#pragma unroll
  for (int it = 0; it < 16; ++it) {
    const int k0 = it * 256 + lane * 4;
    v[it] = *(const float4*)(xr + k0);
    const float a0 = fabsf(v[it].x), a1 = fabsf(v[it].y);
    const float a2 = fabsf(v[it].z), a3 = fabsf(v[it].w);
    amax = fmaxf(amax, fmaxf(fmaxf(a0, a1), fmaxf(a2, a3)));
    if (a0 > SIGMA) mask[k0 + 0] = 1;
    if (a1 > SIGMA) mask[k0 + 1] = 1;
    if (a2 > SIGMA) mask[k0 + 2] = 1;
    if (a3 > SIGMA) mask[k0 + 3] = 1;
  }
#pragma unroll
  for (int off = 32; off > 0; off >>= 1)
    amax = fmaxf(amax, __shfl_xor(amax, off));

  const float s = fmaxf(amax / 127.0f, 1e-8f);
  if (lane == 0) scale_row[m] = s;

  int8_t* qr = qx + (size_t)m * K_TOT;
#pragma unroll
  for (int it = 0; it < 16; ++it) {
    const int k0 = it * 256 + lane * 4;
    const int q0 = (int)rintf(fminf(fmaxf(v[it].x / s, -128.0f), 127.0f));
    const int q1 = (int)rintf(fminf(fmaxf(v[it].y / s, -128.0f), 127.0f));
    const int q2 = (int)rintf(fminf(fmaxf(v[it].z / s, -128.0f), 127.0f));
    const int q3 = (int)rintf(fminf(fmaxf(v[it].w / s, -128.0f), 127.0f));
    const uint32_t p = (uint32_t)(q0 & 0xFF) | ((uint32_t)(q1 & 0xFF) << 8) |
                       ((uint32_t)(q2 & 0xFF) << 16) | ((uint32_t)(q3 & 0xFF) << 24);
    *(uint32_t*)(qr + k0) = p;
  }
}

// ---------------- compact outlier indices (ordered, single block) ----------------
__global__ __launch_bounds__(256) void k_compact(const int* __restrict__ mask,
                                                 uint8_t* __restrict__ bitbytes,
                                                 int* __restrict__ ind,
                                                 int* __restrict__ count) {
  const int t = threadIdx.x;
  int local[16];
  int cnt = 0;
  uint32_t bits = 0;
#pragma unroll
  for (int j = 0; j < 16; ++j) {
    const int k = t * 16 + j;
    if (mask[k]) { bits |= (1u << j); local[cnt++] = k; }
  }
  bitbytes[2 * t]     = (uint8_t)(bits & 0xFF);
  bitbytes[2 * t + 1] = (uint8_t)((bits >> 8) & 0xFF);

  const int lane = t & 63, wid = t >> 6;
  int incl = cnt;
  for (int off = 1; off < 64; off <<= 1) {
    int o = __shfl_up(incl, off);
    if (lane >= off) incl += o;
  }
  __shared__ int wsum[4];
  if (lane == 63) wsum[wid] = incl;
  __syncthreads();
  int base = 0;
  for (int i = 0; i < wid; ++i) base += wsum[i];
  const int excl = base + incl - cnt;
  for (int j = 0; j < cnt; ++j) {
    const int pos = excl + j;
    if (pos < NO_CAP) ind[pos] = local[j];
  }
  if (t == 255) {
    const int tot = excl + cnt;
    *count = tot > NO_CAP ? NO_CAP : tot;
  }
}

// ---------------- weight: zero outlier cols, row absmax -> scale_col, int8 quant, wo gather
__global__ __launch_bounds__(256) void k_quant_w(const float* __restrict__ w,
                                                 const uint8_t* __restrict__ bitbytes,
                                                 const int* __restrict__ ind,
                                                 const int* __restrict__ count,
                                                 int8_t* __restrict__ qw,
                                                 float* __restrict__ scale_col,
                                                 float* __restrict__ wo) {
  const int lane = threadIdx.x & 63;
  const int wid  = threadIdx.x >> 6;
  const int n = blockIdx.x * 4 + wid;
  const float* wr_ = w + (size_t)n * K_TOT;

  float4 v[16];
  float amax = 0.0f;
#pragma unroll
  for (int it = 0; it < 16; ++it) {
    const int k0 = it * 256 + lane * 4;
    v[it] = *(const float4*)(wr_ + k0);
    const uint32_t b = (uint32_t)(bitbytes[k0 >> 3] >> (k0 & 7));
    if (b & 1u) v[it].x = 0.0f;
    if (b & 2u) v[it].y = 0.0f;
    if (b & 4u) v[it].z = 0.0f;
    if (b & 8u) v[it].w = 0.0f;
    amax = fmaxf(amax, fmaxf(fmaxf(fabsf(v[it].x), fabsf(v[it].y)),
                             fmaxf(fabsf(v[it].z), fabsf(v[it].w))));
  }
#pragma unroll
  for (int off = 32; off > 0; off >>= 1)
    amax = fmaxf(amax, __shfl_xor(amax, off));

  float s = amax / 127.0f;
  s = __half2float(__float2half_rn(s));
  s = fmaxf(s, 1e-8f);
  if (lane == 0) scale_col[n] = s;

  int8_t* qr = qw + (size_t)n * K_TOT;
#pragma unroll
  for (int it = 0; it < 16; ++it) {
    const int k0 = it * 256 + lane * 4;
    const int q0 = (int)rintf(fminf(fmaxf(v[it].x / s, -128.0f), 127.0f));
    const int q1 = (int)rintf(fminf(fmaxf(v[it].y / s, -128.0f), 127.0f));
    const int q2 = (int)rintf(fminf(fmaxf(v[it].z / s, -128.0f), 127.0f));
    const int q3 = (int)rintf(fminf(fmaxf(v[it].w / s, -128.0f), 127.0f));
    const uint32_t p = (uint32_t)(q0 & 0xFF) | ((uint32_t)(q1 & 0xFF) << 8) |
                       ((uint32_t)(q2 & 0xFF) << 16) | ((uint32_t)(q3 & 0xFF) << 24);
    *(uint32_t*)(qr + k0) = p;
  }

  const int cnt = *count;
  if (lane < NO_CAP) {
    float val = 0.0f;
    if (lane < cnt) val = wr_[ind[lane]];
    wo[(size_t)n * NO_CAP + lane] = val;
  }
}

// ---------------- gather compact outlier activations (fp32), zero-pad to >=8 ----
__global__ __launch_bounds__(256) void k_gather_xo(const float* __restrict__ x,
                                                   const int* __restrict__ ind,
                                                   const int* __restrict__ count,
                                                   float* __restrict__ xo) {
  const int m = blockIdx.x * 256 + threadIdx.x;
  const int cnt = *count;
  const int fill = cnt < 8 ? 8 : cnt;
  for (int j = 0; j < fill; ++j) {
    float val = 0.0f;
    if (j < cnt) val = x[(size_t)m * K_TOT + ind[j]];
    xo[(size_t)m * NO_CAP + j] = val;
  }
}

// =====================================================================
// int8 GEMM: 256x256 tile, BK=128 bytes, 8-phase schedule — round-4 version
// (known-good 193 µs). Register budget note: acc=128 AGPR + 128 VGPR
// x 2 waves/SIMD saturates the 512-reg unified file; deeper in-register
// read-ahead spills (round-5 lesson).
// =====================================================================
#define STAGE_A(h, kt, bufb) do { \
  __builtin_amdgcn_global_load_lds((const GAS void*)(qx + gAoff[0] + (size_t)(h)*128*K_TOT + (size_t)(kt)*128), \
      (LAS void*)(smem + (bufb)*32768 + (h)*16384 + ldsOff0), 16, 0, 0); \
  __builtin_amdgcn_global_load_lds((const GAS void*)(qx + gAoff[1] + (size_t)(h)*128*K_TOT + (size_t)(kt)*128), \
      (LAS void*)(smem + (bufb)*32768 + (h)*16384 + ldsOff1), 16, 0, 0); \
} while (0)

#define STAGE_B(h, kt, bufb) do { \
  __builtin_amdgcn_global_load_lds((const GAS void*)(qw + gBoff[0] + (size_t)(h)*128*K_TOT + (size_t)(kt)*128), \
      (LAS void*)(smem + 65536 + (bufb)*32768 + (h)*16384 + ldsOff0), 16, 0, 0); \
  __builtin_amdgcn_global_load_lds((const GAS void*)(qw + gBoff[1] + (size_t)(h)*128*K_TOT + (size_t)(kt)*128), \
      (LAS void*)(smem + 65536 + (bufb)*32768 + (h)*16384 + ldsOff1), 16, 0, 0); \
} while (0)

#define LDA(mq, bufb) do { \
  _Pragma("unroll") for (int i_ = 0; i_ < 4; ++i_) \
  _Pragma("unroll") for (int ks_ = 0; ks_ < 2; ++ks_) \
    a[i_][ks_] = *(const v4i*)(smem + aHalfBase + (bufb)*32768 + ((mq)*4 + i_)*2048 + ks_*1024 + rcSwz); \
} while (0)

#define LDB(dst, nq, bufb) do { \
  _Pragma("unroll") for (int i_ = 0; i_ < 2; ++i_) \
  _Pragma("unroll") for (int ks_ = 0; ks_ < 2; ++ks_) \
    dst[i_][ks_] = *(const v4i*)(smem + bHalfBase + (bufb)*32768 + (bColBlk + (nq)*2 + i_)*2048 + ks_*1024 + rcSwz); \
} while (0)

#define MM(mq, nq, bsrc) do { \
  _Pragma("unroll") for (int i_ = 0; i_ < 4; ++i_) \
  _Pragma("unroll") for (int j_ = 0; j_ < 2; ++j_) \
  _Pragma("unroll") for (int ks_ = 0; ks_ < 2; ++ks_) \
    acc[(mq)*4 + i_][(nq)*2 + j_] = __builtin_amdgcn_mfma_i32_16x16x64_i8( \
        a[i_][ks_], bsrc[j_][ks_], acc[(mq)*4 + i_][(nq)*2 + j_], 0, 0, 0); \
} while (0)

#define BAR() __builtin_amdgcn_s_barrier()
#define PHASE_MFMA(mq, nq, bsrc) do { \
  BAR(); \
  asm volatile("s_waitcnt lgkmcnt(0)" ::: "memory"); \
  __builtin_amdgcn_s_setprio(1); \
  MM(mq, nq, bsrc); \
  __builtin_amdgcn_s_setprio(0); \
  BAR(); \
} while (0)

__global__ __launch_bounds__(512, 2) void k_gemm8(const int8_t* __restrict__ qx,
                                                  const int8_t* __restrict__ qw,
                                                  const float* __restrict__ scale_row,
                                                  const float* __restrict__ scale_col,
                                                  const float* __restrict__ xo,
                                                  const float* __restrict__ wo,
                                                  const int* __restrict__ countp,
                                                  const float* __restrict__ bias,
                                                  float* __restrict__ out) {
  extern __shared__ int8_t smem[];
  constexpr int NT = K_TOT / 128;   // 32 K-tiles

  const int t = threadIdx.x;
  const int lane = t & 63;
  const int wid = t >> 6;
  const int wm = wid >> 2;          // 0..1
  const int wn = wid & 3;           // 0..3

  // T1: XCD-aware bijective block swizzle (nwg = 512, divisible by 8)
  const int nbx = gridDim.x;
  const int nwg = gridDim.x * gridDim.y;
  int lin = blockIdx.y * nbx + blockIdx.x;
  lin = (lin & 7) * (nwg >> 3) + (lin >> 3);
  const int bm0 = (lin % nbx) * 256;
  const int bn0 = (lin / nbx) * 256;

  // staging addresses: thread covers 16B chunk f = l*512 + t of a 16KB half-tile
  size_t gAoff[2], gBoff[2];
#pragma unroll
  for (int l = 0; l < 2; ++l) {
    const int f = l * 512 + t;
    const int rb = f >> 7, kb = (f >> 6) & 1, r = (f >> 2) & 15, c16 = f & 3;
    const int c16s = c16 ^ ((r & 8) ? 2 : 0);            // pre-swizzled source chunk
    const int rowInHalf = rb * 16 + r;
    const int colByte = kb * 64 + c16s * 16;
    gAoff[l] = (size_t)(bm0 + rowInHalf) * K_TOT + colByte;
    gBoff[l] = (size_t)(bn0 + rowInHalf) * K_TOT + colByte;
  }
  const int ldsOff0 = wid * 1024;          // wave-uniform; lane*16 added by HW
  const int ldsOff1 = 8192 + wid * 1024;

  // ds_read fragment addressing (swizzled)
  const int rr = lane & 15;
  const int rcSwz = rr * 64 + (((lane >> 4) * 16) ^ ((lane & 8) ? 32 : 0));
  const int aHalfBase = wm * 16384;
  const int bHalfBase = 65536 + (wn >> 1) * 16384;
  const int bColBlk = (wn & 1) * 4;

  v4i acc[8][4];
#pragma unroll
  for (int i = 0; i < 8; ++i)
#pragma unroll
    for (int j = 0; j < 4; ++j) acc[i][j] = (v4i){0, 0, 0, 0};
  v4i a[4][2], b0[2][2], b1[2][2];

  // prologue: stage tile0 (all 4 halves) + tile1's B0,B1,A0 in steady-state order
  STAGE_B(0, 0, 0);
  STAGE_B(1, 0, 0);
  STAGE_A(0, 0, 0);
  STAGE_A(1, 0, 0);
  STAGE_B(0, 1, 1);
  STAGE_B(1, 1, 1);
  STAGE_A(0, 1, 1);
  asm volatile("s_waitcnt vmcnt(6)" ::: "memory");
  BAR();

#pragma unroll 2
  for (int t0 = 0; t0 < NT; ++t0) {
    const int buf = t0 & 1, nbuf = buf ^ 1;
    // ---- phase 0: Q(0,0) ----
    if (t0 + 1 < NT) STAGE_A(1, t0 + 1, nbuf);
    LDA(0, buf);
    LDB(b0, 0, buf);
    PHASE_MFMA(0, 0, b0);
    // ---- phase 1: Q(0,1) ----
    LDB(b1, 1, buf);
    PHASE_MFMA(0, 1, b1);
    // ---- phase 2: Q(1,1) ----
    if (t0 + 2 < NT) STAGE_B(0, t0 + 2, buf);
    LDA(1, buf);
    PHASE_MFMA(1, 1, b1);
    // ---- phase 3: Q(1,0) ----
    if (t0 + 2 < NT) {
      STAGE_B(1, t0 + 2, buf);
      STAGE_A(0, t0 + 2, buf);
    }
    if (t0 < NT - 2) {
      asm volatile("s_waitcnt vmcnt(6)" ::: "memory");
    } else {
      asm volatile("s_waitcnt vmcnt(0)" ::: "memory");
    }
    PHASE_MFMA(1, 0, b0);
  }

  // ---- epilogue: y = acc*sr*sc + outlier_dot + bias, rounded to fp16 precision ----
  const int cnt = *countp;
  const int col = lane & 15;
  const int row4 = (lane >> 4) * 4;

  float scn[4], bzn[4];
  int nn[4];
#pragma unroll
  for (int ni = 0; ni < 4; ++ni) {
    const int n = bn0 + wn * 64 + ni * 16 + col;
    nn[ni] = n;
    scn[ni] = scale_col[n];
    bzn[ni] = bias[n];
  }

  if (cnt <= 8) {
    float wv[4][8];
#pragma unroll
    for (int ni = 0; ni < 4; ++ni)
#pragma unroll
      for (int j = 0; j < 8; ++j) wv[ni][j] = wo[(size_t)nn[ni] * NO_CAP + j];
#pragma unroll
    for (int mi = 0; mi < 8; ++mi) {
#pragma unroll
      for (int r = 0; r < 4; ++r) {
        const int m = bm0 + wm * 128 + mi * 16 + row4 + r;
        const float srm = scale_row[m];
        float xv[8];
#pragma unroll
        for (int j = 0; j < 8; ++j) xv[j] = xo[(size_t)m * NO_CAP + j];
#pragma unroll
        for (int ni = 0; ni < 4; ++ni) {
          float y = (float)acc[mi][ni][r] * srm * scn[ni];
#pragma unroll
          for (int j = 0; j < 8; ++j) y += xv[j] * wv[ni][j];
          y += bzn[ni];
          out[(size_t)m * N_TOT + nn[ni]] = __half2float(__float2half_rn(y));
        }
      }
    }
  } else {
#pragma unroll
    for (int mi = 0; mi < 8; ++mi) {
#pragma unroll
      for (int r = 0; r < 4; ++r) {
        const int m = bm0 + wm * 128 + mi * 16 + row4 + r;
        const float srm = scale_row[m];
#pragma unroll
        for (int ni = 0; ni < 4; ++ni) {
          float y = (float)acc[mi][ni][r] * srm * scn[ni];
          for (int j = 0; j < cnt; ++j)
            y += xo[(size_t)m * NO_CAP + j] * wo[(size_t)nn[ni] * NO_CAP + j];
          y += bzn[ni];
          out[(size_t)m * N_TOT + nn[ni]] = __half2float(__float2half_rn(y));
        }
      }
    }
  }
}

// =====================================================================
// DIAGNOSTIC µbenches (this round only): true in-context MFMA ceilings.
// Issue structure mirrors the GEMM phase: 8 independent acc chains,
// dep-chains of 2, 8 waves/block, 256 blocks (1/CU).
// k_ub16: 1024 x mfma_i32_16x16x64_i8 per wave  (2.10e6 instr total)
//   predicted 17.5 us @3944 TOPS  vs  ~35 us @half-rate
// k_ub32:  512 x mfma_i32_32x32x32_i8 per wave  (1.05e6 instr total)
//   predicted 15.6 us @4404 TOPS  vs  ~31 us @half-rate
// =====================================================================
__global__ __launch_bounds__(512) void k_ub16(int* __restrict__ sink) {
  const int t = threadIdx.x;
  v4i a = { t, t + 1, t + 2, t + 3 };
  v4i b = { t ^ 5, t ^ 9, t ^ 17, t ^ 33 };
  v4i acc[8];
#pragma unroll
  for (int c = 0; c < 8; ++c) acc[c] = (v4i){0, 0, 0, 0};
#pragma unroll 1
  for (int it = 0; it < 64; ++it) {
#pragma unroll
    for (int c = 0; c < 8; ++c) {
      acc[c] = __builtin_amdgcn_mfma_i32_16x16x64_i8(a, b, acc[c], 0, 0, 0);
      acc[c] = __builtin_amdgcn_mfma_i32_16x16x64_i8(a, b, acc[c], 0, 0, 0);
    }
  }
  int s = 0;
#pragma unroll
  for (int c = 0; c < 8; ++c) s += acc[c][0];
  if ((t & 63) == 0) sink[blockIdx.x * 8 + (t >> 6)] = s;
}

__global__ __launch_bounds__(512) void k_ub32(int* __restrict__ sink) {
  const int t = threadIdx.x;
  v4i a = { t, t + 1, t + 2, t + 3 };
  v4i b = { t ^ 5, t ^ 9, t ^ 17, t ^ 33 };
  v16i acc[8];
#pragma unroll
  for (int c = 0; c < 8; ++c)
#pragma unroll
    for (int j = 0; j < 16; ++j) acc[c][j] = 0;
#pragma unroll 1
  for (int it = 0; it < 32; ++it) {
#pragma unroll
    for (int c = 0; c < 8; ++c) {
      acc[c] = __builtin_amdgcn_mfma_i32_32x32x32_i8(a, b, acc[c], 0, 0, 0);
      acc[c] = __builtin_amdgcn_mfma_i32_32x32x32_i8(a, b, acc[c], 0, 0, 0);
    }
  }
  int s = 0;
#pragma unroll
  for (int c = 0; c < 8; ++c) s += acc[c][0];
  if ((t & 63) == 0) sink[blockIdx.x * 8 + (t >> 6)] = s;
}

extern "C" void kernel_launch(void* const* d_in, const int* in_sizes, int n_in,
                              void* d_out, int out_size, void* d_ws, size_t ws_size,
                              hipStream_t stream) {
  const float* x    = (const float*)d_in[0];
  const float* w    = (const float*)d_in[1];
  const float* bias = (const float*)d_in[2];
  float* out        = (float*)d_out;

  const int M = in_sizes[0] / K_TOT;   // 8192 for B=4,S=2048

  char* ws = (char*)d_ws;
  const size_t OFF_SR   = 0;
  const size_t OFF_SC   = OFF_SR + sizeof(float) * (size_t)M;
  const size_t OFF_MASK = OFF_SC + sizeof(float) * (size_t)N_TOT;
  const size_t OFF_IND  = OFF_MASK + sizeof(int) * (size_t)K_TOT;
  const size_t OFF_CNT  = OFF_IND + sizeof(int) * (size_t)NO_CAP;
  const size_t OFF_BB   = OFF_CNT + 256;
  const size_t OFF_XO   = (OFF_BB + (size_t)(K_TOT / 8) + 255) & ~(size_t)255;
  const size_t OFF_WO   = OFF_XO + sizeof(float) * (size_t)M * NO_CAP;
  const size_t OFF_QX   = (OFF_WO + sizeof(float) * (size_t)N_TOT * NO_CAP + 255) & ~(size_t)255;
  const size_t OFF_QW   = OFF_QX + (size_t)M * K_TOT;

  float* scale_row  = (float*)(ws + OFF_SR);
  float* scale_col  = (float*)(ws + OFF_SC);
  int* mask         = (int*)(ws + OFF_MASK);
  int* ind          = (int*)(ws + OFF_IND);
  int* count        = (int*)(ws + OFF_CNT);
  uint8_t* bitbytes = (uint8_t*)(ws + OFF_BB);
  float* xo         = (float*)(ws + OFF_XO);
  float* wo         = (float*)(ws + OFF_WO);
  int8_t* qx        = (int8_t*)(ws + OFF_QX);
  int8_t* qw        = (int8_t*)(ws + OFF_QW);

  // allow 128 KiB dynamic LDS for the 8-phase GEMM
  hipFuncSetAttribute((const void*)k_gemm8,
                      hipFuncAttributeMaxDynamicSharedMemorySize, 131072);

  hipLaunchKernelGGL(k_init, dim3(K_TOT / 256), dim3(256), 0, stream, mask);
  hipLaunchKernelGGL(k_quant_x, dim3(M / 4), dim3(256), 0, stream, x, qx, scale_row, mask);
  hipLaunchKernelGGL(k_compact, dim3(1), dim3(256), 0, stream, mask, bitbytes, ind, count);
  hipLaunchKernelGGL(k_quant_w, dim3(N_TOT / 4), dim3(256), 0, stream,
                     w, bitbytes, ind, count, qw, scale_col, wo);
  hipLaunchKernelGGL(k_gather_xo, dim3(M / 256), dim3(256), 0, stream, x, ind, count, xo);
  hipLaunchKernelGGL(k_gemm8, dim3(M / 256, N_TOT / 256), dim3(512), 131072, stream,
                     qx, qw, scale_row, scale_col, xo, wo, count, bias, out);

  // diagnostic µbenches (write into mask region — dead after k_compact/k_quant_w)
  hipLaunchKernelGGL(k_ub16, dim3(256), dim3(512), 0, stream, mask);
  hipLaunchKernelGGL(k_ub32, dim3(256), dim3(512), 0, stream, mask);
}

// Round 7
// 247.941 us; speedup vs baseline: 1.6577x; 1.1765x over previous
//
#include <hip/hip_runtime.h>
#include <hip/hip_fp16.h>
#include <stdint.h>

#define GAS __attribute__((address_space(1)))
#define LAS __attribute__((address_space(3)))

static constexpr int K_TOT = 4096;
static constexpr int N_TOT = 4096;
static constexpr int NO_CAP = 64;   // max tracked outlier columns (actual data: 8)
static constexpr float SIGMA = 20.0f;

typedef int v4i __attribute__((ext_vector_type(4)));

// ---------------- init: zero outlier mask ----------------
__global__ __launch_bounds__(256) void k_init(int* __restrict__ mask) {
  mask[blockIdx.x * 256 + threadIdx.x] = 0;
}

// ---------------- activation: row absmax -> scale_row, int8 quant, outlier mask ----
__global__ __launch_bounds__(256) void k_quant_x(const float* __restrict__ x,
                                                 int8_t* __restrict__ qx,
                                                 float* __restrict__ scale_row,
                                                 int* __restrict__ mask) {
  const int lane = threadIdx.x & 63;
  const int wid  = threadIdx.x >> 6;
  const int m = blockIdx.x * 4 + wid;
  const float* xr = x + (size_t)m * K_TOT;

  float4 v[16];
  float amax = 0.0f;
#pragma unroll
  for (int it = 0; it < 16; ++it) {
    const int k0 = it * 256 + lane * 4;
    v[it] = *(const float4*)(xr + k0);
    const float a0 = fabsf(v[it].x), a1 = fabsf(v[it].y);
    const float a2 = fabsf(v[it].z), a3 = fabsf(v[it].w);
    amax = fmaxf(amax, fmaxf(fmaxf(a0, a1), fmaxf(a2, a3)));
    if (a0 > SIGMA) mask[k0 + 0] = 1;
    if (a1 > SIGMA) mask[k0 + 1] = 1;
    if (a2 > SIGMA) mask[k0 + 2] = 1;
    if (a3 > SIGMA) mask[k0 + 3] = 1;
  }
#pragma unroll
  for (int off = 32; off > 0; off >>= 1)
    amax = fmaxf(amax, __shfl_xor(amax, off));

  const float s = fmaxf(amax / 127.0f, 1e-8f);
  if (lane == 0) scale_row[m] = s;

  int8_t* qr = qx + (size_t)m * K_TOT;
#pragma unroll
  for (int it = 0; it < 16; ++it) {
    const int k0 = it * 256 + lane * 4;
    const int q0 = (int)rintf(fminf(fmaxf(v[it].x / s, -128.0f), 127.0f));
    const int q1 = (int)rintf(fminf(fmaxf(v[it].y / s, -128.0f), 127.0f));
    const int q2 = (int)rintf(fminf(fmaxf(v[it].z / s, -128.0f), 127.0f));
    const int q3 = (int)rintf(fminf(fmaxf(v[it].w / s, -128.0f), 127.0f));
    const uint32_t p = (uint32_t)(q0 & 0xFF) | ((uint32_t)(q1 & 0xFF) << 8) |
                       ((uint32_t)(q2 & 0xFF) << 16) | ((uint32_t)(q3 & 0xFF) << 24);
    *(uint32_t*)(qr + k0) = p;
  }
}

// ---------------- compact outlier indices (ordered, single block) ----------------
__global__ __launch_bounds__(256) void k_compact(const int* __restrict__ mask,
                                                 uint8_t* __restrict__ bitbytes,
                                                 int* __restrict__ ind,
                                                 int* __restrict__ count) {
  const int t = threadIdx.x;
  int local[16];
  int cnt = 0;
  uint32_t bits = 0;
#pragma unroll
  for (int j = 0; j < 16; ++j) {
    const int k = t * 16 + j;
    if (mask[k]) { bits |= (1u << j); local[cnt++] = k; }
  }
  bitbytes[2 * t]     = (uint8_t)(bits & 0xFF);
  bitbytes[2 * t + 1] = (uint8_t)((bits >> 8) & 0xFF);

  const int lane = t & 63, wid = t >> 6;
  int incl = cnt;
  for (int off = 1; off < 64; off <<= 1) {
    int o = __shfl_up(incl, off);
    if (lane >= off) incl += o;
  }
  __shared__ int wsum[4];
  if (lane == 63) wsum[wid] = incl;
  __syncthreads();
  int base = 0;
  for (int i = 0; i < wid; ++i) base += wsum[i];
  const int excl = base + incl - cnt;
  for (int j = 0; j < cnt; ++j) {
    const int pos = excl + j;
    if (pos < NO_CAP) ind[pos] = local[j];
  }
  if (t == 255) {
    const int tot = excl + cnt;
    *count = tot > NO_CAP ? NO_CAP : tot;
  }
}

// ---------------- weight: zero outlier cols, row absmax -> scale_col, int8 quant, wo gather
__global__ __launch_bounds__(256) void k_quant_w(const float* __restrict__ w,
                                                 const uint8_t* __restrict__ bitbytes,
                                                 const int* __restrict__ ind,
                                                 const int* __restrict__ count,
                                                 int8_t* __restrict__ qw,
                                                 float* __restrict__ scale_col,
                                                 float* __restrict__ wo) {
  const int lane = threadIdx.x & 63;
  const int wid  = threadIdx.x >> 6;
  const int n = blockIdx.x * 4 + wid;
  const float* wr_ = w + (size_t)n * K_TOT;

  float4 v[16];
  float amax = 0.0f;
#pragma unroll
  for (int it = 0; it < 16; ++it) {
    const int k0 = it * 256 + lane * 4;
    v[it] = *(const float4*)(wr_ + k0);
    const uint32_t b = (uint32_t)(bitbytes[k0 >> 3] >> (k0 & 7));
    if (b & 1u) v[it].x = 0.0f;
    if (b & 2u) v[it].y = 0.0f;
    if (b & 4u) v[it].z = 0.0f;
    if (b & 8u) v[it].w = 0.0f;
    amax = fmaxf(amax, fmaxf(fmaxf(fabsf(v[it].x), fabsf(v[it].y)),
                             fmaxf(fabsf(v[it].z), fabsf(v[it].w))));
  }
#pragma unroll
  for (int off = 32; off > 0; off >>= 1)
    amax = fmaxf(amax, __shfl_xor(amax, off));

  float s = amax / 127.0f;
  s = __half2float(__float2half_rn(s));
  s = fmaxf(s, 1e-8f);
  if (lane == 0) scale_col[n] = s;

  int8_t* qr = qw + (size_t)n * K_TOT;
#pragma unroll
  for (int it = 0; it < 16; ++it) {
    const int k0 = it * 256 + lane * 4;
    const int q0 = (int)rintf(fminf(fmaxf(v[it].x / s, -128.0f), 127.0f));
    const int q1 = (int)rintf(fminf(fmaxf(v[it].y / s, -128.0f), 127.0f));
    const int q2 = (int)rintf(fminf(fmaxf(v[it].z / s, -128.0f), 127.0f));
    const int q3 = (int)rintf(fminf(fmaxf(v[it].w / s, -128.0f), 127.0f));
    const uint32_t p = (uint32_t)(q0 & 0xFF) | ((uint32_t)(q1 & 0xFF) << 8) |
                       ((uint32_t)(q2 & 0xFF) << 16) | ((uint32_t)(q3 & 0xFF) << 24);
    *(uint32_t*)(qr + k0) = p;
  }

  const int cnt = *count;
  if (lane < NO_CAP) {
    float val = 0.0f;
    if (lane < cnt) val = wr_[ind[lane]];
    wo[(size_t)n * NO_CAP + lane] = val;
  }
}

// ---------------- gather compact outlier activations (fp32), zero-pad to >=8 ----
__global__ __launch_bounds__(256) void k_gather_xo(const float* __restrict__ x,
                                                   const int* __restrict__ ind,
                                                   const int* __restrict__ count,
                                                   float* __restrict__ xo) {
  const int m = blockIdx.x * 256 + threadIdx.x;
  const int cnt = *count;
  const int fill = cnt < 8 ? 8 : cnt;
  for (int j = 0; j < fill; ++j) {
    float val = 0.0f;
    if (j < cnt) val = x[(size_t)m * K_TOT + ind[j]];
    xo[(size_t)m * NO_CAP + j] = val;
  }
}

// =====================================================================
// int8 GEMM: 256x256 tile, BK=128 bytes, 4-phase/K-tile, ONE barrier per
// phase (pre-MFMA). vs round 4: removed the post-MFMA barrier and the
// manual lgkmcnt(0) drain. Mechanism: with 2 barriers/phase all waves
// drain LDS in lockstep -> LDS service (≈960cy) serializes with MFMA
// (653cy) = 1815cy/phase measured. One barrier lets waves slip <=1 phase:
// next phase's ds_reads are serviced under the MFMA tail of slow waves,
// and compiler-counted lgkm waits let early MFMAs start before late reads
// land. Hazards audited: reads target buffers staged >=2 tiles back;
// stage-issue WAR is ordered through the pre-MFMA barrier; vmcnt(6)
// ledger at p3 unchanged.
// Register budget: acc=128 AGPR + 128 VGPR x 2 waves/SIMD = full 512-reg
// file; NO extra live state allowed (round-5 spill lesson).
// =====================================================================
#define STAGE_A(h, kt, bufb) do { \
  __builtin_amdgcn_global_load_lds((const GAS void*)(qx + gAoff[0] + (size_t)(h)*128*K_TOT + (size_t)(kt)*128), \
      (LAS void*)(smem + (bufb)*32768 + (h)*16384 + ldsOff0), 16, 0, 0); \
  __builtin_amdgcn_global_load_lds((const GAS void*)(qx + gAoff[1] + (size_t)(h)*128*K_TOT + (size_t)(kt)*128), \
      (LAS void*)(smem + (bufb)*32768 + (h)*16384 + ldsOff1), 16, 0, 0); \
} while (0)

#define STAGE_B(h, kt, bufb) do { \
  __builtin_amdgcn_global_load_lds((const GAS void*)(qw + gBoff[0] + (size_t)(h)*128*K_TOT + (size_t)(kt)*128), \
      (LAS void*)(smem + 65536 + (bufb)*32768 + (h)*16384 + ldsOff0), 16, 0, 0); \
  __builtin_amdgcn_global_load_lds((const GAS void*)(qw + gBoff[1] + (size_t)(h)*128*K_TOT + (size_t)(kt)*128), \
      (LAS void*)(smem + 65536 + (bufb)*32768 + (h)*16384 + ldsOff1), 16, 0, 0); \
} while (0)

#define LDA(mq, bufb) do { \
  _Pragma("unroll") for (int i_ = 0; i_ < 4; ++i_) \
  _Pragma("unroll") for (int ks_ = 0; ks_ < 2; ++ks_) \
    a[i_][ks_] = *(const v4i*)(smem + aHalfBase + (bufb)*32768 + ((mq)*4 + i_)*2048 + ks_*1024 + rcSwz); \
} while (0)

#define LDB(dst, nq, bufb) do { \
  _Pragma("unroll") for (int i_ = 0; i_ < 2; ++i_) \
  _Pragma("unroll") for (int ks_ = 0; ks_ < 2; ++ks_) \
    dst[i_][ks_] = *(const v4i*)(smem + bHalfBase + (bufb)*32768 + (bColBlk + (nq)*2 + i_)*2048 + ks_*1024 + rcSwz); \
} while (0)

#define MM(mq, nq, bsrc) do { \
  _Pragma("unroll") for (int i_ = 0; i_ < 4; ++i_) \
  _Pragma("unroll") for (int j_ = 0; j_ < 2; ++j_) \
  _Pragma("unroll") for (int ks_ = 0; ks_ < 2; ++ks_) \
    acc[(mq)*4 + i_][(nq)*2 + j_] = __builtin_amdgcn_mfma_i32_16x16x64_i8( \
        a[i_][ks_], bsrc[j_][ks_], acc[(mq)*4 + i_][(nq)*2 + j_], 0, 0, 0); \
} while (0)

#define BAR() __builtin_amdgcn_s_barrier()
// ONE barrier per phase, before the MFMA cluster; no manual lgkm drain
// (compiler emits counted waits for its own ds_read->MFMA deps).
#define PHASE_MFMA(mq, nq, bsrc) do { \
  BAR(); \
  __builtin_amdgcn_s_setprio(1); \
  MM(mq, nq, bsrc); \
  __builtin_amdgcn_s_setprio(0); \
} while (0)

__global__ __launch_bounds__(512, 2) void k_gemm8(const int8_t* __restrict__ qx,
                                                  const int8_t* __restrict__ qw,
                                                  const float* __restrict__ scale_row,
                                                  const float* __restrict__ scale_col,
                                                  const float* __restrict__ xo,
                                                  const float* __restrict__ wo,
                                                  const int* __restrict__ countp,
                                                  const float* __restrict__ bias,
                                                  float* __restrict__ out) {
  extern __shared__ int8_t smem[];
  constexpr int NT = K_TOT / 128;   // 32 K-tiles

  const int t = threadIdx.x;
  const int lane = t & 63;
  const int wid = t >> 6;
  const int wm = wid >> 2;          // 0..1
  const int wn = wid & 3;           // 0..3

  // T1: XCD-aware bijective block swizzle (nwg = 512, divisible by 8)
  const int nbx = gridDim.x;
  const int nwg = gridDim.x * gridDim.y;
  int lin = blockIdx.y * nbx + blockIdx.x;
  lin = (lin & 7) * (nwg >> 3) + (lin >> 3);
  const int bm0 = (lin % nbx) * 256;
  const int bn0 = (lin / nbx) * 256;

  // staging addresses: thread covers 16B chunk f = l*512 + t of a 16KB half-tile
  size_t gAoff[2], gBoff[2];
#pragma unroll
  for (int l = 0; l < 2; ++l) {
    const int f = l * 512 + t;
    const int rb = f >> 7, kb = (f >> 6) & 1, r = (f >> 2) & 15, c16 = f & 3;
    const int c16s = c16 ^ ((r & 8) ? 2 : 0);            // pre-swizzled source chunk
    const int rowInHalf = rb * 16 + r;
    const int colByte = kb * 64 + c16s * 16;
    gAoff[l] = (size_t)(bm0 + rowInHalf) * K_TOT + colByte;
    gBoff[l] = (size_t)(bn0 + rowInHalf) * K_TOT + colByte;
  }
  const int ldsOff0 = wid * 1024;          // wave-uniform; lane*16 added by HW
  const int ldsOff1 = 8192 + wid * 1024;

  // ds_read fragment addressing (swizzled)
  const int rr = lane & 15;
  const int rcSwz = rr * 64 + (((lane >> 4) * 16) ^ ((lane & 8) ? 32 : 0));
  const int aHalfBase = wm * 16384;
  const int bHalfBase = 65536 + (wn >> 1) * 16384;
  const int bColBlk = (wn & 1) * 4;

  v4i acc[8][4];
#pragma unroll
  for (int i = 0; i < 8; ++i)
#pragma unroll
    for (int j = 0; j < 4; ++j) acc[i][j] = (v4i){0, 0, 0, 0};
  v4i a[4][2], b0[2][2], b1[2][2];

  // prologue: stage tile0 (all 4 halves) + tile1's B0,B1,A0 in steady-state order
  STAGE_B(0, 0, 0);
  STAGE_B(1, 0, 0);
  STAGE_A(0, 0, 0);
  STAGE_A(1, 0, 0);
  STAGE_B(0, 1, 1);
  STAGE_B(1, 1, 1);
  STAGE_A(0, 1, 1);
  asm volatile("s_waitcnt vmcnt(6)" ::: "memory");
  BAR();

#pragma unroll 2
  for (int t0 = 0; t0 < NT; ++t0) {
    const int buf = t0 & 1, nbuf = buf ^ 1;
    // ---- phase 0: Q(0,0) ----
    if (t0 + 1 < NT) STAGE_A(1, t0 + 1, nbuf);
    LDA(0, buf);
    LDB(b0, 0, buf);
    PHASE_MFMA(0, 0, b0);
    // ---- phase 1: Q(0,1) ----
    LDB(b1, 1, buf);
    PHASE_MFMA(0, 1, b1);
    // ---- phase 2: Q(1,1) ----
    if (t0 + 2 < NT) STAGE_B(0, t0 + 2, buf);
    LDA(1, buf);
    PHASE_MFMA(1, 1, b1);
    // ---- phase 3: Q(1,0) ----
    if (t0 + 2 < NT) {
      STAGE_B(1, t0 + 2, buf);
      STAGE_A(0, t0 + 2, buf);
    }
    if (t0 < NT - 2) {
      asm volatile("s_waitcnt vmcnt(6)" ::: "memory");
    } else {
      asm volatile("s_waitcnt vmcnt(0)" ::: "memory");
    }
    PHASE_MFMA(1, 0, b0);
  }

  // all waves' last MFMA done before epilogue overwrites nothing shared — no barrier needed
  // ---- epilogue: y = acc*sr*sc + outlier_dot + bias, rounded to fp16 precision ----
  const int cnt = *countp;
  const int col = lane & 15;
  const int row4 = (lane >> 4) * 4;

  float scn[4], bzn[4];
  int nn[4];
#pragma unroll
  for (int ni = 0; ni < 4; ++ni) {
    const int n = bn0 + wn * 64 + ni * 16 + col;
    nn[ni] = n;
    scn[ni] = scale_col[n];
    bzn[ni] = bias[n];
  }

  if (cnt <= 8) {
    float wv[4][8];
#pragma unroll
    for (int ni = 0; ni < 4; ++ni)
#pragma unroll
      for (int j = 0; j < 8; ++j) wv[ni][j] = wo[(size_t)nn[ni] * NO_CAP + j];
#pragma unroll
    for (int mi = 0; mi < 8; ++mi) {
#pragma unroll
      for (int r = 0; r < 4; ++r) {
        const int m = bm0 + wm * 128 + mi * 16 + row4 + r;
        const float srm = scale_row[m];
        float xv[8];
#pragma unroll
        for (int j = 0; j < 8; ++j) xv[j] = xo[(size_t)m * NO_CAP + j];
#pragma unroll
        for (int ni = 0; ni < 4; ++ni) {
          float y = (float)acc[mi][ni][r] * srm * scn[ni];
#pragma unroll
          for (int j = 0; j < 8; ++j) y += xv[j] * wv[ni][j];
          y += bzn[ni];
          out[(size_t)m * N_TOT + nn[ni]] = __half2float(__float2half_rn(y));
        }
      }
    }
  } else {
#pragma unroll
    for (int mi = 0; mi < 8; ++mi) {
#pragma unroll
      for (int r = 0; r < 4; ++r) {
        const int m = bm0 + wm * 128 + mi * 16 + row4 + r;
        const float srm = scale_row[m];
#pragma unroll
        for (int ni = 0; ni < 4; ++ni) {
          float y = (float)acc[mi][ni][r] * srm * scn[ni];
          for (int j = 0; j < cnt; ++j)
            y += xo[(size_t)m * NO_CAP + j] * wo[(size_t)nn[ni] * NO_CAP + j];
          y += bzn[ni];
          out[(size_t)m * N_TOT + nn[ni]] = __half2float(__float2half_rn(y));
        }
      }
    }
  }
}

extern "C" void kernel_launch(void* const* d_in, const int* in_sizes, int n_in,
                              void* d_out, int out_size, void* d_ws, size_t ws_size,
                              hipStream_t stream) {
  const float* x    = (const float*)d_in[0];
  const float* w    = (const float*)d_in[1];
  const float* bias = (const float*)d_in[2];
  float* out        = (float*)d_out;

  const int M = in_sizes[0] / K_TOT;   // 8192 for B=4,S=2048

  char* ws = (char*)d_ws;
  const size_t OFF_SR   = 0;
  const size_t OFF_SC   = OFF_SR + sizeof(float) * (size_t)M;
  const size_t OFF_MASK = OFF_SC + sizeof(float) * (size_t)N_TOT;
  const size_t OFF_IND  = OFF_MASK + sizeof(int) * (size_t)K_TOT;
  const size_t OFF_CNT  = OFF_IND + sizeof(int) * (size_t)NO_CAP;
  const size_t OFF_BB   = OFF_CNT + 256;
  const size_t OFF_XO   = (OFF_BB + (size_t)(K_TOT / 8) + 255) & ~(size_t)255;
  const size_t OFF_WO   = OFF_XO + sizeof(float) * (size_t)M * NO_CAP;
  const size_t OFF_QX   = (OFF_WO + sizeof(float) * (size_t)N_TOT * NO_CAP + 255) & ~(size_t)255;
  const size_t OFF_QW   = OFF_QX + (size_t)M * K_TOT;

  float* scale_row  = (float*)(ws + OFF_SR);
  float* scale_col  = (float*)(ws + OFF_SC);
  int* mask         = (int*)(ws + OFF_MASK);
  int* ind          = (int*)(ws + OFF_IND);
  int* count        = (int*)(ws + OFF_CNT);
  uint8_t* bitbytes = (uint8_t*)(ws + OFF_BB);
  float* xo         = (float*)(ws + OFF_XO);
  float* wo         = (float*)(ws + OFF_WO);
  int8_t* qx        = (int8_t*)(ws + OFF_QX);
  int8_t* qw        = (int8_t*)(ws + OFF_QW);

  // allow 128 KiB dynamic LDS for the 8-phase GEMM
  hipFuncSetAttribute((const void*)k_gemm8,
                      hipFuncAttributeMaxDynamicSharedMemorySize, 131072);

  hipLaunchKernelGGL(k_init, dim3(K_TOT / 256), dim3(256), 0, stream, mask);
  hipLaunchKernelGGL(k_quant_x, dim3(M / 4), dim3(256), 0, stream, x, qx, scale_row, mask);
  hipLaunchKernelGGL(k_compact, dim3(1), dim3(256), 0, stream, mask, bitbytes, ind, count);
  hipLaunchKernelGGL(k_quant_w, dim3(N_TOT / 4), dim3(256), 0, stream,
                     w, bitbytes, ind, count, qw, scale_col, wo);
  hipLaunchKernelGGL(k_gather_xo, dim3(M / 256), dim3(256), 0, stream, x, ind, count, xo);
  hipLaunchKernelGGL(k_gemm8, dim3(M / 256, N_TOT / 256), dim3(512), 131072, stream,
                     qx, qw, scale_row, scale_col, xo, wo, count, bias, out);
}